// Round 7
// baseline (207.691 us; speedup 1.0000x reference)
//
#include <hip/hip_runtime.h>

typedef __attribute__((ext_vector_type(8))) __bf16 bf16x8;
typedef __attribute__((ext_vector_type(8))) unsigned short ushort8;
typedef __attribute__((ext_vector_type(4))) unsigned short ushort4v;
typedef __attribute__((ext_vector_type(4))) float f32x4;
typedef __attribute__((ext_vector_type(2))) _Float16 f16x2;
typedef __attribute__((ext_vector_type(4))) _Float16 f16x4;
typedef __attribute__((ext_vector_type(8))) _Float16 f16x8;
typedef __attribute__((ext_vector_type(2))) __fp16 fp16v2;

__device__ __forceinline__ unsigned short f2bf(float f) {
    union { float f; unsigned int u; } c; c.f = f;
    unsigned int u = c.u;
    u += 0x7fffu + ((u >> 16) & 1u);
    return (unsigned short)(u >> 16);
}

// async global->LDS, 16 B per lane; LDS dest = wave-uniform base + lane*16
__device__ __forceinline__ void async16(const void* g, void* l) {
    __builtin_amdgcn_global_load_lds(
        (const __attribute__((address_space(1))) unsigned int*)g,
        (__attribute__((address_space(3))) unsigned int*)l, 16, 0, 0);
}

// ---------------- fused fp32 -> bf16 conversion for all 5 tensors ----------------
__global__ __launch_bounds__(256) void cvt_all(
    const float* __restrict__ q,  const float* __restrict__ wq,
    const float* __restrict__ wk, const float* __restrict__ wv,
    const float* __restrict__ wo,
    unsigned short* __restrict__ q_bf, unsigned short* __restrict__ wqkv,
    unsigned short* __restrict__ wo_bf, float scale_k)
{
    const int NQ = 4096 * 1024, NW = 1024 * 1024;
    int i = (blockIdx.x * 256 + threadIdx.x) * 4;
    const float* src; unsigned short* dst; float sc = 1.0f; int off;
    if (i < NQ)               { src = q;  dst = q_bf;          off = i; }
    else if (i < NQ + NW)     { src = wq; dst = wqkv;          off = i - NQ; }
    else if (i < NQ + 2 * NW) { src = wk; dst = wqkv + NW;     off = i - NQ - NW; sc = scale_k; }
    else if (i < NQ + 3 * NW) { src = wv; dst = wqkv + 2 * NW; off = i - NQ - 2 * NW; }
    else                      { src = wo; dst = wo_bf;         off = i - NQ - 3 * NW; }
    float4 v = *(const float4*)(src + off);
    ushort4v o;
    o[0] = f2bf(v.x * sc); o[1] = f2bf(v.y * sc);
    o[2] = f2bf(v.z * sc); o[3] = f2bf(v.w * sc);
    *(ushort4v*)(dst + off) = o;
}

// ---------------- qkv = q_bf[4096,1024] @ wqkv[3072,1024]^T + bias (bf16 out) ----------------
// unchanged from r6 (3 blocks/CU — dbuf known-neutral at that occupancy, m99/m100)
__global__ __launch_bounds__(256) void qkv_gemm(
    const unsigned short* __restrict__ A,
    const unsigned short* __restrict__ B,
    unsigned short* __restrict__ Cout,
    const float* __restrict__ b0, const float* __restrict__ b1, const float* __restrict__ b2,
    float s1)
{
    __shared__ __align__(16) unsigned short As[128 * 64];
    __shared__ __align__(16) unsigned short Bs[128 * 64];

    const int tid  = threadIdx.x;
    const int lane = tid & 63, wave = tid >> 6;
    const int quad = lane >> 4, l15 = lane & 15;
    const int wm = wave >> 1, wn = wave & 1;
    const int by = blockIdx.y, bx = blockIdx.x;
    const int K = 1024, N = 3072;

    const int srow = lane >> 3;
    const int sp   = lane & 7;
    const int scl  = sp ^ srow;
    const int sw   = l15 & 7;

    f32x4 acc[4][4];
#pragma unroll
    for (int i = 0; i < 4; ++i)
#pragma unroll
        for (int j = 0; j < 4; ++j) acc[i][j] = (f32x4)(0.0f);

    for (int kt = 0; kt < 16; ++kt) {
        __syncthreads();
#pragma unroll
        for (int j = 0; j < 4; ++j) {
            int r0 = wave * 32 + j * 8;
            async16(A + (size_t)(by * 128 + r0 + srow) * K + kt * 64 + scl * 8, &As[r0 * 64]);
            async16(B + (size_t)(bx * 128 + r0 + srow) * K + kt * 64 + scl * 8, &Bs[r0 * 64]);
        }
        __syncthreads();

#pragma unroll
        for (int kh = 0; kh < 2; ++kh) {
            bf16x8 af[4], bfr[4];
#pragma unroll
            for (int mi = 0; mi < 4; ++mi)
                af[mi] = __builtin_bit_cast(bf16x8,
                    *(const ushort8*)&As[(wm * 64 + mi * 16 + l15) * 64 + ((kh * 4 + quad) ^ sw) * 8]);
#pragma unroll
            for (int ni = 0; ni < 4; ++ni)
                bfr[ni] = __builtin_bit_cast(bf16x8,
                    *(const ushort8*)&Bs[(wn * 64 + ni * 16 + l15) * 64 + ((kh * 4 + quad) ^ sw) * 8]);
#pragma unroll
            for (int mi = 0; mi < 4; ++mi)
#pragma unroll
                for (int ni = 0; ni < 4; ++ni)
                    acc[mi][ni] = __builtin_amdgcn_mfma_f32_16x16x32_bf16(af[mi], bfr[ni], acc[mi][ni], 0, 0, 0);
        }
    }

#pragma unroll
    for (int ni = 0; ni < 4; ++ni) {
        int n = bx * 128 + wn * 64 + ni * 16 + l15;
        float bias = (n < 1024) ? b0[n] : (n < 2048 ? b1[n - 1024] * s1 : b2[n - 2048]);
#pragma unroll
        for (int mi = 0; mi < 4; ++mi) {
#pragma unroll
            for (int r = 0; r < 4; ++r) {
                int m = by * 128 + wm * 64 + mi * 16 + quad * 4 + r;
                Cout[(size_t)m * N + n] = f2bf(acc[mi][ni][r] + bias);
            }
        }
    }
}

// ---------------- out = ctx[4096,1024] @ wo[1024,1024]^T + bo (fp32 out) ----------------
// 128x64 tile, 512 blocks = 2/CU. Double-buffered single-barrier K-loop:
// prefetch tile t+1 issued right after the barrier, full tile of compute before drain.
__global__ __launch_bounds__(256) void out_gemm(
    const unsigned short* __restrict__ A,
    const unsigned short* __restrict__ B,
    float* __restrict__ Cout,
    const float* __restrict__ bo)
{
    __shared__ __align__(16) unsigned short As[2][128 * 64];
    __shared__ __align__(16) unsigned short Bs[2][64 * 64];

    const int tid  = threadIdx.x;
    const int lane = tid & 63, wave = tid >> 6;
    const int quad = lane >> 4, l15 = lane & 15;
    const int wm = wave >> 1, wn = wave & 1;
    const int by = blockIdx.y, bx = blockIdx.x;
    const int K = 1024;

    const int srow = lane >> 3;
    const int sp   = lane & 7;
    const int scl  = sp ^ srow;
    const int sw   = l15 & 7;

    f32x4 acc[4][2];
#pragma unroll
    for (int i = 0; i < 4; ++i)
#pragma unroll
        for (int j = 0; j < 2; ++j) acc[i][j] = (f32x4)(0.0f);

    auto stage = [&](int kt, int p) {
#pragma unroll
        for (int j = 0; j < 4; ++j) {
            int r0 = wave * 32 + j * 8;
            async16(A + (size_t)(by * 128 + r0 + srow) * K + kt * 64 + scl * 8, &As[p][r0 * 64]);
        }
#pragma unroll
        for (int j = 0; j < 2; ++j) {
            int r0 = wave * 16 + j * 8;
            async16(B + (size_t)(bx * 64 + r0 + srow) * K + kt * 64 + scl * 8, &Bs[p][r0 * 64]);
        }
    };

    auto compute = [&](int p) {
#pragma unroll
        for (int kh = 0; kh < 2; ++kh) {
            bf16x8 af[4], bfr[2];
#pragma unroll
            for (int mi = 0; mi < 4; ++mi)
                af[mi] = __builtin_bit_cast(bf16x8,
                    *(const ushort8*)&As[p][(wm * 64 + mi * 16 + l15) * 64 + ((kh * 4 + quad) ^ sw) * 8]);
#pragma unroll
            for (int ni = 0; ni < 2; ++ni)
                bfr[ni] = __builtin_bit_cast(bf16x8,
                    *(const ushort8*)&Bs[p][(wn * 32 + ni * 16 + l15) * 64 + ((kh * 4 + quad) ^ sw) * 8]);
#pragma unroll
            for (int mi = 0; mi < 4; ++mi)
#pragma unroll
                for (int ni = 0; ni < 2; ++ni)
                    acc[mi][ni] = __builtin_amdgcn_mfma_f32_16x16x32_bf16(af[mi], bfr[ni], acc[mi][ni], 0, 0, 0);
        }
    };

    stage(0, 0);
    for (int t = 0; t < 8; ++t) {
        __syncthreads();                 // drains buf0 prefetch (had a full tile in flight)
        stage(2 * t + 1, 1);
        compute(0);
        __syncthreads();                 // drains buf1 prefetch
        if (t < 7) stage(2 * t + 2, 0);
        compute(1);
    }

#pragma unroll
    for (int ni = 0; ni < 2; ++ni) {
        int n = bx * 64 + wn * 32 + ni * 16 + l15;
        float bias = bo[n];
#pragma unroll
        for (int mi = 0; mi < 4; ++mi) {
#pragma unroll
            for (int r = 0; r < 4; ++r) {
                int m = by * 128 + wm * 64 + mi * 16 + quad * 4 + r;
                Cout[(size_t)m * 1024 + n] = acc[mi][ni][r] + bias;
            }
        }
    }
}

// ---------------- V transpose -> vtg [bh][hd][S] f16, PV-permuted + XOR-swizzled ----------------
__global__ __launch_bounds__(256) void transpose_v(const unsigned short* __restrict__ qkv,
                                                   _Float16* __restrict__ vtg)
{
    __shared__ unsigned short Ls[64][68];
    const int tid = threadIdx.x;
    const int bh = blockIdx.y, st = blockIdx.x;
    const int b = bh >> 4, h = bh & 15;

#pragma unroll
    for (int i = 0; i < 2; ++i) {
        int s = tid + i * 256;
        int row = s >> 3, c8 = (s & 7) << 3;
        ushort8 v = *(const ushort8*)(qkv + (size_t)(b * 2048 + st * 64 + row) * 3072 + 2048 + h * 64 + c8);
        *(ushort8*)&Ls[row][c8] = v;
    }
    __syncthreads();
#pragma unroll
    for (int i = 0; i < 2; ++i) {
        int s = tid + i * 256;
        int hd = s >> 3, p = s & 7;
        int cl = p ^ (hd & 7);
        int g = cl >> 2, q = cl & 3;
        f16x8 o;
#pragma unroll
        for (int e = 0; e < 8; ++e) {
            int kv = g * 32 + (e >> 2) * 16 + q * 4 + (e & 3);
            union { float f; unsigned int u; } c;
            c.u = ((unsigned int)Ls[kv][hd]) << 16;
            o[e] = (_Float16)c.f;
        }
        *(f16x8*)(vtg + (size_t)(bh * 64 + hd) * 2048 + st * 64 + p * 8) = o;
    }
}

// ---------------- flash attention v5: r6 compute + double-buffered K/V staging ----------------
// One barrier per KV-tile; prefetch of tile kt+1 issued immediately after the barrier,
// so the next barrier's vmcnt drain finds loads that had a full tile of compute in flight.
__global__ __launch_bounds__(256) void attn(const unsigned short* __restrict__ qkv,
                                            const _Float16* __restrict__ vtg,
                                            unsigned short* __restrict__ ctx)
{
    __shared__ __align__(16) unsigned short Ks[2][64 * 64];
    __shared__ __align__(16) _Float16 Vt[2][64 * 64];

    const int tid  = threadIdx.x;
    const int lane = tid & 63, wave = tid >> 6;
    const int quad = lane >> 4, l15 = lane & 15;
    const int bh = blockIdx.y;
    const int b = bh >> 4, h = bh & 15;
    const int q0 = blockIdx.x * 128;

    const int srow = lane >> 3;
    const int sp   = lane & 7;
    const int scl  = sp ^ srow;
    const int sw   = l15 & 7;

    auto stage = [&](int kt, int p) {
#pragma unroll
        for (int i = 0; i < 2; ++i) {
            int row = i * 32 + wave * 8 + srow;
            async16(qkv + (size_t)(b * 2048 + kt * 64 + row) * 3072 + 1024 + h * 64 + scl * 8,
                    &Ks[p][(i * 32 + wave * 8) * 64]);
            async16(vtg + (size_t)(bh * 64 + row) * 2048 + kt * 64 + sp * 8,
                    (unsigned short*)&Vt[p][(i * 32 + wave * 8) * 64]);
        }
    };

    stage(0, 0);

    bf16x8 qf[2][2];
#pragma unroll
    for (int s = 0; s < 2; ++s) {
        int qrow = b * 2048 + q0 + wave * 32 + s * 16 + l15;
#pragma unroll
        for (int kh = 0; kh < 2; ++kh)
            qf[s][kh] = __builtin_bit_cast(bf16x8,
                *(const ushort8*)(qkv + (size_t)qrow * 3072 + h * 64 + kh * 32 + quad * 8));
    }

    f32x4 ot[2][4];
#pragma unroll
    for (int s = 0; s < 2; ++s)
#pragma unroll
        for (int ht = 0; ht < 4; ++ht) ot[s][ht] = (f32x4)(0.0f);
    float l_acc[2] = {0.0f, 0.0f};
    const fp16v2 ones = {(__fp16)1.0f, (__fp16)1.0f};

    auto compute = [&](int p) {
        f16x4 pv[2][4];
#pragma unroll
        for (int mt = 0; mt < 4; ++mt) {
            const unsigned short* kb = &Ks[p][(mt * 16 + l15) * 64];
            bf16x8 k0 = __builtin_bit_cast(bf16x8, *(const ushort8*)(kb + (quad ^ sw) * 8));
            bf16x8 k1 = __builtin_bit_cast(bf16x8, *(const ushort8*)(kb + ((quad ^ sw) ^ 4) * 8));
#pragma unroll
            for (int s = 0; s < 2; ++s) {
                f32x4 s4 = (f32x4)(0.0f);
                s4 = __builtin_amdgcn_mfma_f32_16x16x32_bf16(k0, qf[s][0], s4, 0, 0, 0);
                s4 = __builtin_amdgcn_mfma_f32_16x16x32_bf16(k1, qf[s][1], s4, 0, 0, 0);
                float p0 = __builtin_amdgcn_exp2f(s4[0]);
                float p1 = __builtin_amdgcn_exp2f(s4[1]);
                float p2 = __builtin_amdgcn_exp2f(s4[2]);
                float p3 = __builtin_amdgcn_exp2f(s4[3]);
                fp16v2 lo = __builtin_amdgcn_cvt_pkrtz(p0, p1);
                fp16v2 hi = __builtin_amdgcn_cvt_pkrtz(p2, p3);
                l_acc[s] = __builtin_amdgcn_fdot2(lo, ones, l_acc[s], false);
                l_acc[s] = __builtin_amdgcn_fdot2(hi, ones, l_acc[s], false);
                f16x2 lo2 = __builtin_bit_cast(f16x2, lo);
                f16x2 hi2 = __builtin_bit_cast(f16x2, hi);
                pv[s][mt] = __builtin_shufflevector(lo2, hi2, 0, 1, 2, 3);
            }
        }

#pragma unroll
        for (int ht = 0; ht < 4; ++ht) {
            const _Float16* vb = &Vt[p][(ht * 16 + l15) * 64];
#pragma unroll
            for (int g = 0; g < 2; ++g) {
                f16x8 v8 = *(const f16x8*)(vb + (((g * 4 + quad) ^ sw)) * 8);
                f16x4 vlo = __builtin_shufflevector(v8, v8, 0, 1, 2, 3);
                f16x4 vhi = __builtin_shufflevector(v8, v8, 4, 5, 6, 7);
#pragma unroll
                for (int s = 0; s < 2; ++s) {
                    ot[s][ht] = __builtin_amdgcn_mfma_f32_16x16x16f16(vlo, pv[s][2 * g],     ot[s][ht], 0, 0, 0);
                    ot[s][ht] = __builtin_amdgcn_mfma_f32_16x16x16f16(vhi, pv[s][2 * g + 1], ot[s][ht], 0, 0, 0);
                }
            }
        }
    };

    for (int t = 0; t < 16; ++t) {
        __syncthreads();                  // buf0 ready (prefetched a full tile ago)
        stage(2 * t + 1, 1);
        compute(0);
        __syncthreads();                  // buf1 ready
        if (t < 15) stage(2 * t + 2, 0);
        compute(1);
    }

#pragma unroll
    for (int s = 0; s < 2; ++s) {
        float l = l_acc[s];
        l += __shfl_xor(l, 16, 64);
        l += __shfl_xor(l, 32, 64);
        float inv = 1.0f / l;
        int qrow = b * 2048 + q0 + wave * 32 + s * 16 + l15;
#pragma unroll
        for (int ht = 0; ht < 4; ++ht) {
            ushort4v o4;
#pragma unroll
            for (int r = 0; r < 4; ++r) o4[r] = f2bf(ot[s][ht][r] * inv);
            *(ushort4v*)(ctx + (size_t)qrow * 1024 + h * 64 + ht * 16 + quad * 4) = o4;
        }
    }
}

extern "C" void kernel_launch(void* const* d_in, const int* in_sizes, int n_in,
                              void* d_out, int out_size, void* d_ws, size_t ws_size,
                              hipStream_t stream) {
    const float* query = (const float*)d_in[0];
    const float* Wq = (const float*)d_in[1];
    const float* bq = (const float*)d_in[2];
    const float* Wk = (const float*)d_in[3];
    const float* bk = (const float*)d_in[4];
    const float* Wv = (const float*)d_in[5];
    const float* bv = (const float*)d_in[6];
    const float* Wo = (const float*)d_in[7];
    const float* bo = (const float*)d_in[8];

    char* ws = (char*)d_ws;
    unsigned short* q_bf  = (unsigned short*)(ws);                 // 8 MB (dead after qkv_gemm)
    _Float16*       vtg   = (_Float16*)(ws);                       // aliases q_bf
    unsigned short* wqkv  = (unsigned short*)(ws + 8388608);
    unsigned short* wo_bf = (unsigned short*)(ws + 14680064);
    unsigned short* qkv   = (unsigned short*)(ws + 16777216);
    unsigned short* ctx   = (unsigned short*)(ws + 41943040);

    const float SCALE = 0.125f * 1.4426950408889634f;   // (1/sqrt(hd)) * log2(e), folded into K

    cvt_all<<<8192, 256, 0, stream>>>(query, Wq, Wk, Wv, Wo, q_bf, wqkv, wo_bf, SCALE);
    qkv_gemm<<<dim3(24, 32), 256, 0, stream>>>(q_bf, wqkv, qkv, bq, bk, bv, SCALE);
    transpose_v<<<dim3(32, 32), 256, 0, stream>>>(qkv, vtg);
    attn<<<dim3(16, 32), 256, 0, stream>>>(qkv, vtg, ctx);
    out_gemm<<<dim3(16, 32), 256, 0, stream>>>(ctx, wo_bf, (float*)d_out, bo);
}

// Round 8
// 195.455 us; speedup vs baseline: 1.0626x; 1.0626x over previous
//
#include <hip/hip_runtime.h>

typedef __attribute__((ext_vector_type(8))) __bf16 bf16x8;
typedef __attribute__((ext_vector_type(8))) unsigned short ushort8;
typedef __attribute__((ext_vector_type(4))) unsigned short ushort4v;
typedef __attribute__((ext_vector_type(4))) float f32x4;
typedef __attribute__((ext_vector_type(2))) _Float16 f16x2;
typedef __attribute__((ext_vector_type(4))) _Float16 f16x4;
typedef __attribute__((ext_vector_type(8))) _Float16 f16x8;
typedef __attribute__((ext_vector_type(2))) __fp16 fp16v2;

__device__ __forceinline__ unsigned short f2bf(float f) {
    union { float f; unsigned int u; } c; c.f = f;
    unsigned int u = c.u;
    u += 0x7fffu + ((u >> 16) & 1u);
    return (unsigned short)(u >> 16);
}

// async global->LDS, 16 B per lane; LDS dest = wave-uniform base + lane*16
__device__ __forceinline__ void async16(const void* g, void* l) {
    __builtin_amdgcn_global_load_lds(
        (const __attribute__((address_space(1))) unsigned int*)g,
        (__attribute__((address_space(3))) unsigned int*)l, 16, 0, 0);
}

// ---------------- fused fp32 -> bf16 conversion for all 5 tensors ----------------
__global__ __launch_bounds__(256) void cvt_all(
    const float* __restrict__ q,  const float* __restrict__ wq,
    const float* __restrict__ wk, const float* __restrict__ wv,
    const float* __restrict__ wo,
    unsigned short* __restrict__ q_bf, unsigned short* __restrict__ wqkv,
    unsigned short* __restrict__ wo_bf, float scale_k)
{
    const int NQ = 4096 * 1024, NW = 1024 * 1024;
    int i = (blockIdx.x * 256 + threadIdx.x) * 4;
    const float* src; unsigned short* dst; float sc = 1.0f; int off;
    if (i < NQ)               { src = q;  dst = q_bf;          off = i; }
    else if (i < NQ + NW)     { src = wq; dst = wqkv;          off = i - NQ; }
    else if (i < NQ + 2 * NW) { src = wk; dst = wqkv + NW;     off = i - NQ - NW; sc = scale_k; }
    else if (i < NQ + 3 * NW) { src = wv; dst = wqkv + 2 * NW; off = i - NQ - 2 * NW; }
    else                      { src = wo; dst = wo_bf;         off = i - NQ - 3 * NW; }
    float4 v = *(const float4*)(src + off);
    ushort4v o;
    o[0] = f2bf(v.x * sc); o[1] = f2bf(v.y * sc);
    o[2] = f2bf(v.z * sc); o[3] = f2bf(v.w * sc);
    *(ushort4v*)(dst + off) = o;
}

// ---------------- qkv_gemm: [query]@[Wq;Wk;Wv]^T + bias ----------------
// Q,K columns (bx<16) -> qkv [4096][2048] bf16.
// V columns (bx>=16)  -> written DIRECTLY to vtg [bh][hd][S] f16 with the PV
// permutation + XOR swizzle (transpose is free from the C-layout: each lane owns
// a fixed feature column = fixed hd, 4-token runs -> 8B f16x4 stores).
__global__ __launch_bounds__(256) void qkv_gemm(
    const unsigned short* __restrict__ A,
    const unsigned short* __restrict__ B,
    unsigned short* __restrict__ qkv,
    _Float16* __restrict__ vtg,
    const float* __restrict__ b0, const float* __restrict__ b1, const float* __restrict__ b2,
    float s1)
{
    __shared__ __align__(16) unsigned short As[128 * 64];
    __shared__ __align__(16) unsigned short Bs[128 * 64];

    const int tid  = threadIdx.x;
    const int lane = tid & 63, wave = tid >> 6;
    const int quad = lane >> 4, l15 = lane & 15;
    const int wm = wave >> 1, wn = wave & 1;
    const int by = blockIdx.y, bx = blockIdx.x;
    const int K = 1024;

    const int srow = lane >> 3;
    const int sp   = lane & 7;
    const int scl  = sp ^ srow;
    const int sw   = l15 & 7;

    f32x4 acc[4][4];
#pragma unroll
    for (int i = 0; i < 4; ++i)
#pragma unroll
        for (int j = 0; j < 4; ++j) acc[i][j] = (f32x4)(0.0f);

    for (int kt = 0; kt < 16; ++kt) {
        __syncthreads();
#pragma unroll
        for (int j = 0; j < 4; ++j) {
            int r0 = wave * 32 + j * 8;
            async16(A + (size_t)(by * 128 + r0 + srow) * K + kt * 64 + scl * 8, &As[r0 * 64]);
            async16(B + (size_t)(bx * 128 + r0 + srow) * K + kt * 64 + scl * 8, &Bs[r0 * 64]);
        }
        __syncthreads();

#pragma unroll
        for (int kh = 0; kh < 2; ++kh) {
            bf16x8 af[4], bfr[4];
#pragma unroll
            for (int mi = 0; mi < 4; ++mi)
                af[mi] = __builtin_bit_cast(bf16x8,
                    *(const ushort8*)&As[(wm * 64 + mi * 16 + l15) * 64 + ((kh * 4 + quad) ^ sw) * 8]);
#pragma unroll
            for (int ni = 0; ni < 4; ++ni)
                bfr[ni] = __builtin_bit_cast(bf16x8,
                    *(const ushort8*)&Bs[(wn * 64 + ni * 16 + l15) * 64 + ((kh * 4 + quad) ^ sw) * 8]);
#pragma unroll
            for (int mi = 0; mi < 4; ++mi)
#pragma unroll
                for (int ni = 0; ni < 4; ++ni)
                    acc[mi][ni] = __builtin_amdgcn_mfma_f32_16x16x32_bf16(af[mi], bfr[ni], acc[mi][ni], 0, 0, 0);
        }
    }

    if (bx < 16) {
#pragma unroll
        for (int ni = 0; ni < 4; ++ni) {
            int n = bx * 128 + wn * 64 + ni * 16 + l15;
            float bias = (n < 1024) ? b0[n] : b1[n - 1024] * s1;
#pragma unroll
            for (int mi = 0; mi < 4; ++mi) {
#pragma unroll
                for (int r = 0; r < 4; ++r) {
                    int m = by * 128 + wm * 64 + mi * 16 + quad * 4 + r;
                    qkv[(size_t)m * 2048 + n] = f2bf(acc[mi][ni][r] + bias);
                }
            }
        }
    } else {
        // V region: vf = feature 0..1023; lane owns fixed hd, tokens in 4-runs.
        // kv = mi*16 + quad*4 + r; g = mi>>1, q = quad, e = (mi&1)*4+r,
        // p = (g*4+quad)^(hd&7); hd&7 == l15&7.
        const int mb = by * 128 + wm * 64;
        const int b  = mb >> 11;
        const int st = (mb & 2047) >> 6;
#pragma unroll
        for (int ni = 0; ni < 4; ++ni) {
            int vf = (bx - 16) * 128 + wn * 64 + ni * 16 + l15;
            int h = vf >> 6, hd = vf & 63;
            float bias = b2[vf];
            _Float16* vrow = vtg + ((size_t)((b * 16 + h) * 64 + hd)) * 2048 + st * 64;
#pragma unroll
            for (int mi = 0; mi < 4; ++mi) {
                int p = ((mi >> 1) * 4 + quad) ^ (l15 & 7);
                f16x4 o;
#pragma unroll
                for (int r = 0; r < 4; ++r) o[r] = (_Float16)(acc[mi][ni][r] + bias);
                *(f16x4*)(vrow + p * 8 + (mi & 1) * 4) = o;
            }
        }
    }
}

// ---------------- out = ctx[4096,1024] @ wo[1024,1024]^T + bo (fp32 out) ----------------
// r6 single-buffer version (dbuf measured neutral in r7).
__global__ __launch_bounds__(256) void out_gemm(
    const unsigned short* __restrict__ A,
    const unsigned short* __restrict__ B,
    float* __restrict__ Cout,
    const float* __restrict__ bo)
{
    __shared__ __align__(16) unsigned short As[128 * 64];
    __shared__ __align__(16) unsigned short Bs[64 * 64];

    const int tid  = threadIdx.x;
    const int lane = tid & 63, wave = tid >> 6;
    const int quad = lane >> 4, l15 = lane & 15;
    const int wm = wave >> 1, wn = wave & 1;
    const int by = blockIdx.y, bx = blockIdx.x;
    const int K = 1024;

    const int srow = lane >> 3;
    const int sp   = lane & 7;
    const int scl  = sp ^ srow;
    const int sw   = l15 & 7;

    f32x4 acc[4][2];
#pragma unroll
    for (int i = 0; i < 4; ++i)
#pragma unroll
        for (int j = 0; j < 2; ++j) acc[i][j] = (f32x4)(0.0f);

    for (int kt = 0; kt < 16; ++kt) {
        __syncthreads();
#pragma unroll
        for (int j = 0; j < 4; ++j) {
            int r0 = wave * 32 + j * 8;
            async16(A + (size_t)(by * 128 + r0 + srow) * K + kt * 64 + scl * 8, &As[r0 * 64]);
        }
#pragma unroll
        for (int j = 0; j < 2; ++j) {
            int r0 = wave * 16 + j * 8;
            async16(B + (size_t)(bx * 64 + r0 + srow) * K + kt * 64 + scl * 8, &Bs[r0 * 64]);
        }
        __syncthreads();

#pragma unroll
        for (int kh = 0; kh < 2; ++kh) {
            bf16x8 af[4], bfr[2];
#pragma unroll
            for (int mi = 0; mi < 4; ++mi)
                af[mi] = __builtin_bit_cast(bf16x8,
                    *(const ushort8*)&As[(wm * 64 + mi * 16 + l15) * 64 + ((kh * 4 + quad) ^ sw) * 8]);
#pragma unroll
            for (int ni = 0; ni < 2; ++ni)
                bfr[ni] = __builtin_bit_cast(bf16x8,
                    *(const ushort8*)&Bs[(wn * 32 + ni * 16 + l15) * 64 + ((kh * 4 + quad) ^ sw) * 8]);
#pragma unroll
            for (int mi = 0; mi < 4; ++mi)
#pragma unroll
                for (int ni = 0; ni < 2; ++ni)
                    acc[mi][ni] = __builtin_amdgcn_mfma_f32_16x16x32_bf16(af[mi], bfr[ni], acc[mi][ni], 0, 0, 0);
        }
    }

#pragma unroll
    for (int ni = 0; ni < 2; ++ni) {
        int n = bx * 64 + wn * 32 + ni * 16 + l15;
        float bias = bo[n];
#pragma unroll
        for (int mi = 0; mi < 4; ++mi) {
#pragma unroll
            for (int r = 0; r < 4; ++r) {
                int m = by * 128 + wm * 64 + mi * 16 + quad * 4 + r;
                Cout[(size_t)m * 1024 + n] = acc[mi][ni][r] + bias;
            }
        }
    }
}

// ---------------- flash attention (r6-validated structure; qkv stride 2048) ----------------
__global__ __launch_bounds__(256) void attn(const unsigned short* __restrict__ qkv,
                                            const _Float16* __restrict__ vtg,
                                            unsigned short* __restrict__ ctx)
{
    __shared__ __align__(16) unsigned short Ks[64 * 64];
    __shared__ __align__(16) _Float16 Vt[64 * 64];

    const int tid  = threadIdx.x;
    const int lane = tid & 63, wave = tid >> 6;
    const int quad = lane >> 4, l15 = lane & 15;
    const int bh = blockIdx.y;
    const int b = bh >> 4, h = bh & 15;
    const int q0 = blockIdx.x * 128;

    const int srow = lane >> 3;
    const int sp   = lane & 7;
    const int scl  = sp ^ srow;
    const int sw   = l15 & 7;

    bf16x8 qf[2][2];
#pragma unroll
    for (int s = 0; s < 2; ++s) {
        int qrow = b * 2048 + q0 + wave * 32 + s * 16 + l15;
#pragma unroll
        for (int kh = 0; kh < 2; ++kh)
            qf[s][kh] = __builtin_bit_cast(bf16x8,
                *(const ushort8*)(qkv + (size_t)qrow * 2048 + h * 64 + kh * 32 + quad * 8));
    }

    f32x4 ot[2][4];
#pragma unroll
    for (int s = 0; s < 2; ++s)
#pragma unroll
        for (int ht = 0; ht < 4; ++ht) ot[s][ht] = (f32x4)(0.0f);
    float l_acc[2] = {0.0f, 0.0f};
    const fp16v2 ones = {(__fp16)1.0f, (__fp16)1.0f};

    for (int kt = 0; kt < 32; ++kt) {
        __syncthreads();
#pragma unroll
        for (int i = 0; i < 2; ++i) {
            int row = i * 32 + wave * 8 + srow;
            async16(qkv + (size_t)(b * 2048 + kt * 64 + row) * 2048 + 1024 + h * 64 + scl * 8,
                    &Ks[(i * 32 + wave * 8) * 64]);
            async16(vtg + (size_t)(bh * 64 + row) * 2048 + kt * 64 + sp * 8,
                    (unsigned short*)&Vt[(i * 32 + wave * 8) * 64]);
        }
        __syncthreads();

        f16x4 pv[2][4];
#pragma unroll
        for (int mt = 0; mt < 4; ++mt) {
            const unsigned short* kb = &Ks[(mt * 16 + l15) * 64];
            bf16x8 k0 = __builtin_bit_cast(bf16x8, *(const ushort8*)(kb + (quad ^ sw) * 8));
            bf16x8 k1 = __builtin_bit_cast(bf16x8, *(const ushort8*)(kb + ((quad ^ sw) ^ 4) * 8));
#pragma unroll
            for (int s = 0; s < 2; ++s) {
                f32x4 s4 = (f32x4)(0.0f);
                s4 = __builtin_amdgcn_mfma_f32_16x16x32_bf16(k0, qf[s][0], s4, 0, 0, 0);
                s4 = __builtin_amdgcn_mfma_f32_16x16x32_bf16(k1, qf[s][1], s4, 0, 0, 0);
                float p0 = __builtin_amdgcn_exp2f(s4[0]);
                float p1 = __builtin_amdgcn_exp2f(s4[1]);
                float p2 = __builtin_amdgcn_exp2f(s4[2]);
                float p3 = __builtin_amdgcn_exp2f(s4[3]);
                fp16v2 lo = __builtin_amdgcn_cvt_pkrtz(p0, p1);
                fp16v2 hi = __builtin_amdgcn_cvt_pkrtz(p2, p3);
                l_acc[s] = __builtin_amdgcn_fdot2(lo, ones, l_acc[s], false);
                l_acc[s] = __builtin_amdgcn_fdot2(hi, ones, l_acc[s], false);
                f16x2 lo2 = __builtin_bit_cast(f16x2, lo);
                f16x2 hi2 = __builtin_bit_cast(f16x2, hi);
                pv[s][mt] = __builtin_shufflevector(lo2, hi2, 0, 1, 2, 3);
            }
        }

#pragma unroll
        for (int ht = 0; ht < 4; ++ht) {
            const _Float16* vb = &Vt[(ht * 16 + l15) * 64];
#pragma unroll
            for (int g = 0; g < 2; ++g) {
                f16x8 v8 = *(const f16x8*)(vb + (((g * 4 + quad) ^ sw)) * 8);
                f16x4 vlo = __builtin_shufflevector(v8, v8, 0, 1, 2, 3);
                f16x4 vhi = __builtin_shufflevector(v8, v8, 4, 5, 6, 7);
#pragma unroll
                for (int s = 0; s < 2; ++s) {
                    ot[s][ht] = __builtin_amdgcn_mfma_f32_16x16x16f16(vlo, pv[s][2 * g],     ot[s][ht], 0, 0, 0);
                    ot[s][ht] = __builtin_amdgcn_mfma_f32_16x16x16f16(vhi, pv[s][2 * g + 1], ot[s][ht], 0, 0, 0);
                }
            }
        }
    }

#pragma unroll
    for (int s = 0; s < 2; ++s) {
        float l = l_acc[s];
        l += __shfl_xor(l, 16, 64);
        l += __shfl_xor(l, 32, 64);
        float inv = 1.0f / l;
        int qrow = b * 2048 + q0 + wave * 32 + s * 16 + l15;
#pragma unroll
        for (int ht = 0; ht < 4; ++ht) {
            ushort4v o4;
#pragma unroll
            for (int r = 0; r < 4; ++r) o4[r] = f2bf(ot[s][ht][r] * inv);
            *(ushort4v*)(ctx + (size_t)qrow * 1024 + h * 64 + ht * 16 + quad * 4) = o4;
        }
    }
}

extern "C" void kernel_launch(void* const* d_in, const int* in_sizes, int n_in,
                              void* d_out, int out_size, void* d_ws, size_t ws_size,
                              hipStream_t stream) {
    const float* query = (const float*)d_in[0];
    const float* Wq = (const float*)d_in[1];
    const float* bq = (const float*)d_in[2];
    const float* Wk = (const float*)d_in[3];
    const float* bk = (const float*)d_in[4];
    const float* Wv = (const float*)d_in[5];
    const float* bv = (const float*)d_in[6];
    const float* Wo = (const float*)d_in[7];
    const float* bo = (const float*)d_in[8];

    char* ws = (char*)d_ws;
    unsigned short* q_bf  = (unsigned short*)(ws);                 // 8 MB (dead after qkv_gemm)
    unsigned short* ctx   = (unsigned short*)(ws);                 // aliases q_bf (attn writes after q_bf dead)
    unsigned short* wqkv  = (unsigned short*)(ws + 8388608);       // 6 MB
    unsigned short* wo_bf = (unsigned short*)(ws + 14680064);      // 2 MB
    unsigned short* qkv   = (unsigned short*)(ws + 16777216);      // [4096][2048] bf16 = 16 MB (Q,K only)
    _Float16*       vtg   = (_Float16*)(ws + 33554432);            // [32][64][2048] f16 = 8 MB

    const float SCALE = 0.125f * 1.4426950408889634f;   // (1/sqrt(hd)) * log2(e), folded into K

    cvt_all<<<8192, 256, 0, stream>>>(query, Wq, Wk, Wv, Wo, q_bf, wqkv, wo_bf, SCALE);
    qkv_gemm<<<dim3(24, 32), 256, 0, stream>>>(q_bf, wqkv, qkv, vtg, bq, bk, bv, SCALE);
    attn<<<dim3(16, 32), 256, 0, stream>>>(qkv, vtg, ctx);
    out_gemm<<<dim3(16, 32), 256, 0, stream>>>(ctx, wo_bf, (float*)d_out, bo);
}